// Round 5
// baseline (140.106 us; speedup 1.0000x reference)
//
#include <hip/hip_runtime.h>

typedef __bf16 bf16x8 __attribute__((ext_vector_type(8)));
typedef float f32x4 __attribute__((ext_vector_type(4)));

#define GLOAD_LDS16(g, l)                                                      \
  __builtin_amdgcn_global_load_lds(                                            \
      (const __attribute__((address_space(1))) void*)(g),                      \
      (__attribute__((address_space(3))) void*)(l), 16, 0, 0)

// R14: 3-launch pipeline.
//  K1 k_prep: blocks 0..NB-1 normalize ALL rows in ORIGINAL order (no deps);
//             last block does the label scan -> map/gcode/hdr (runs
//             concurrently -- no intra-kernel dependency between the two).
//  K2 k_p1:  gathers via map[] on the global_load_lds SOURCE address (per-lane
//            source, linear LDS dest). Otherwise identical to R13.
//  K3 k_p2:  unchanged from R13 (operates in gathered index space).
// P stays [slot][row] transposed. Pads map to the first valid row (finite
// data; every downstream use is masked by gcode==255).

// ---------------- K1: fused normalize-all + scan ----------------------------
__global__ __launch_bounds__(512) void k_prep(
    const float* __restrict__ X, const int* __restrict__ labels,
    const int* __restrict__ bad, int* __restrict__ map,
    int* __restrict__ hdr, __bf16* __restrict__ fn,
    unsigned char* __restrict__ gcode, float* __restrict__ out, int Nv,
    int Dv, int NB) {
  const int t = threadIdx.x;
  if ((int)blockIdx.x < NB) {
    // ---- normalize 8 rows (one per wave), original order, ALL rows ----
    const int tl = t & 63;
    const int row = blockIdx.x * 8 + (t >> 6);
    if (row >= Nv) return;
    const float4* xr = (const float4*)(X + (size_t)row * Dv);
    if (Dv == 512) {
      const float4 v0 = xr[tl * 2];
      const float4 v1 = xr[tl * 2 + 1];
      float ss = v0.x * v0.x + v0.y * v0.y + v0.z * v0.z + v0.w * v0.w +
                 v1.x * v1.x + v1.y * v1.y + v1.z * v1.z + v1.w * v1.w;
#pragma unroll
      for (int off = 1; off < 64; off <<= 1) ss += __shfl_xor(ss, off);
      const float inv = 1.0f / sqrtf(ss);
      bf16x8 o;
      o[0] = (__bf16)(v0.x * inv);
      o[1] = (__bf16)(v0.y * inv);
      o[2] = (__bf16)(v0.z * inv);
      o[3] = (__bf16)(v0.w * inv);
      o[4] = (__bf16)(v1.x * inv);
      o[5] = (__bf16)(v1.y * inv);
      o[6] = (__bf16)(v1.z * inv);
      o[7] = (__bf16)(v1.w * inv);
      *(bf16x8*)(fn + (size_t)row * Dv + tl * 8) = o;
      return;
    }
    // generic path
    float ss = 0.f;
    for (int idx = tl; idx < (Dv >> 2); idx += 64) {
      const float4 v = xr[idx];
      ss += v.x * v.x + v.y * v.y + v.z * v.z + v.w * v.w;
    }
#pragma unroll
    for (int off = 1; off < 64; off <<= 1) ss += __shfl_xor(ss, off);
    const float inv = 1.0f / sqrtf(ss);
    for (int idx = tl; idx < (Dv >> 3); idx += 64) {
      const float4 u0 = xr[idx * 2];
      const float4 u1 = xr[idx * 2 + 1];
      bf16x8 o;
      o[0] = (__bf16)(u0.x * inv);
      o[1] = (__bf16)(u0.y * inv);
      o[2] = (__bf16)(u0.z * inv);
      o[3] = (__bf16)(u0.w * inv);
      o[4] = (__bf16)(u1.x * inv);
      o[5] = (__bf16)(u1.y * inv);
      o[6] = (__bf16)(u1.z * inv);
      o[7] = (__bf16)(u1.w * inv);
      *(bf16x8*)(fn + (size_t)row * Dv + idx * 8) = o;
    }
    return;
  }

  // ---- scan block (last): label partition -> map/gcode/hdr ----
  const int lane = t & 63, wv = t >> 6;
  const int per = Nv >> 9;  // rows/thread (16 at 8192)
  const int base = t * per;
  unsigned char lc[64];  // per <= 64 supported
  int cnt[3] = {0, 0, 0};
  {  // int4-vectorized loads: per is a multiple of 4
    const int4* l4 = (const int4*)(labels + base);
    const int4* b4 = (const int4*)(bad + base);
    for (int k = 0; k < (per >> 2); ++k) {
      const int4 lv = l4[k];
      const int4 bv = b4[k];
      const int la[4] = {lv.x, lv.y, lv.z, lv.w};
      const int ba[4] = {bv.x, bv.y, bv.z, bv.w};
#pragma unroll
      for (int e = 0; e < 4; ++e) {
        const unsigned char c =
            (ba[e] == 0) ? (unsigned char)la[e] : (unsigned char)255;
        lc[k * 4 + e] = c;
        if (c <= 2) cnt[c]++;
      }
    }
  }
  int inc0 = cnt[0], inc1 = cnt[1], inc2 = cnt[2];
#pragma unroll
  for (int off = 1; off < 64; off <<= 1) {
    const int a = __shfl_up(inc0, off);
    const int b = __shfl_up(inc1, off);
    const int c = __shfl_up(inc2, off);
    if (lane >= off) {
      inc0 += a;
      inc1 += b;
      inc2 += c;
    }
  }
  __shared__ int wt[8][3], wo[9][3];
  __shared__ int first_valid;
  if (lane == 63) {
    wt[wv][0] = inc0;
    wt[wv][1] = inc1;
    wt[wv][2] = inc2;
  }
  __syncthreads();
  if (t == 0) {
    int s0 = 0, s1 = 0, s2 = 0;
    for (int w = 0; w < 8; ++w) {
      wo[w][0] = s0;
      wo[w][1] = s1;
      wo[w][2] = s2;
      s0 += wt[w][0];
      s1 += wt[w][1];
      s2 += wt[w][2];
    }
    wo[8][0] = s0;
    wo[8][1] = s1;
    wo[8][2] = s2;
  }
  __syncthreads();
  const int C0 = wo[8][0], C1 = wo[8][1], C2 = wo[8][2];
  int run[3];
  run[0] = wo[wv][0] + inc0 - cnt[0];
  run[1] = C0 + wo[wv][1] + inc1 - cnt[1];
  run[2] = C0 + C1 + wo[wv][2] + inc2 - cnt[2];
  for (int k = 0; k < per; ++k) {
    const int c = lc[k];
    if (c <= 2) {
      const int d = run[c]++;
      map[d] = base + k;     // gathered g -> original row
      gcode[d] = (unsigned char)c;
      if (d == 0) first_valid = base + k;
    }
  }
  const int M = C0 + C1 + C2;
  const int Mpad = (M + 127) & ~127;
  if (t == 0) {
    const int NTv = Mpad >> 7;
    hdr[0] = M;
    hdr[1] = Mpad;
    hdr[2] = NTv;
    hdr[3] = NTv * (NTv + 1) / 2;
    hdr[4] = C0;
    hdr[5] = C1;
    hdr[6] = C2;
    // count = 1 + #(processed & has_pos)
    int count = 1;
    if (C0 >= 2 && M > C0) count += C0;
    if (C1 >= 2 && M > C1) count += C1;
    if (C2 >= 2 && M > C2) count += C2;
    hdr[7] = count;
    out[0] = 0.f;  // k_p2 atomicAdds into this
  }
  __syncthreads();  // first_valid visible
  const int fv = (M > 0) ? first_valid : 0;
  for (int i = M + t; i < Mpad; i += 512) {
    gcode[i] = 255;   // pad: self-masking label
    map[i] = fv;      // pad: stage finite data (masked everywhere)
  }
}

__device__ __forceinline__ void tri_decode(int blk, int NT, int& bi, int& bj) {
  int b = 0, rem = blk, span = NT;
  while (rem >= span) {
    rem -= span;
    b++;
    span--;
  }
  bi = b;
  bj = b + rem;
}

// bijective XCD swizzle over [0,n) (m204 formula)
__device__ __forceinline__ int xcd_swz(int w, int n) {
  const int q = n >> 3, r = n & 7, x = w & 7, o = w >> 3;
  return (x < r ? x * (q + 1) : r * (q + 1) + (x - r) * q) + o;
}

__device__ __forceinline__ bool tile_overlap(const unsigned char* gcode,
                                             size_t sA, int lastA,
                                             size_t rowB) {
  const int la0 = gcode[sA], la1 = gcode[sA + lastA];
  const int lb0 = gcode[rowB], lb1 = gcode[rowB + 127];
  const int hiA = la1 > 2 ? 2 : la1;
  const int hiB = lb1 > 2 ? 2 : lb1;
  const int lo = la0 > lb0 ? la0 : lb0;
  const int hi = hiA < hiB ? hiA : hiB;
  return (la0 <= 2) && (lb0 <= 2) && (lo <= hi);
}

// ---------------- K2: pass 1 — exp-sums, 128x128 tiles, map-gathered --------
__global__ __launch_bounds__(512, 6) void k_p1(
    const __bf16* __restrict__ fn, const int* __restrict__ map,
    const unsigned char* __restrict__ gcode, const int* __restrict__ hdr,
    float* __restrict__ P, _Float16* __restrict__ Sc, int Nv, int Dv) {
  const int NTv = hdr[2];
  const int ntri = hdr[3];
  int bid = blockIdx.x;
  if (bid >= ntri) return;
  bid = xcd_swz(bid, ntri);
  int bi, bj;
  tri_decode(bid, NTv, bi, bj);
  const size_t sA = (size_t)bi * 128;
  const size_t rowB = (size_t)bj * 128;
  __shared__ __align__(16) __bf16 As[2][128 * 32];
  __shared__ __align__(16) __bf16 Bs[2][128 * 32];

  const int t = threadIdx.x;
  const int lane = t & 63;
  const int wave = t >> 6;
  const int quad = lane >> 4;
  const int l16 = lane & 15;
  const int wr = (wave >> 1) * 32;
  const int wc = (wave & 1) * 64;
  const int r4 = t >> 2, q4 = t & 3;

  // gather indirection: per-lane SOURCE row, loaded once (r4 fixed per thread)
  const size_t ma = (size_t)map[sA + r4] * Dv;
  const size_t mb = (size_t)map[rowB + r4] * Dv;

  f32x4 acc[2][4] = {};
  auto stage = [&](int k0, int b) {
    GLOAD_LDS16(fn + ma + k0 + q4 * 8, &As[b][(size_t)wave * 64 * 8]);
    GLOAD_LDS16(fn + mb + k0 + q4 * 8, &Bs[b][(size_t)wave * 64 * 8]);
  };
  stage(0, 0);
  int buf = 0;
  for (int k0 = 0; k0 < Dv; k0 += 32) {
    __syncthreads();  // drains vmcnt: buf loads done; prev reads done
    if (k0 + 32 < Dv) stage(k0 + 32, buf ^ 1);
    bf16x8 af[2], bfv[4];
#pragma unroll
    for (int mi = 0; mi < 2; ++mi)
      af[mi] = *(const bf16x8*)&As[buf][(wr + mi * 16 + l16) * 32 + quad * 8];
#pragma unroll
    for (int ni = 0; ni < 4; ++ni)
      bfv[ni] = *(const bf16x8*)&Bs[buf][(wc + ni * 16 + l16) * 32 + quad * 8];
#pragma unroll
    for (int mi = 0; mi < 2; ++mi)
#pragma unroll
      for (int ni = 0; ni < 4; ++ni)
        acc[mi][ni] = __builtin_amdgcn_mfma_f32_16x16x32_bf16(
            af[mi], bfv[ni], acc[mi][ni], 0, 0, 0);
    buf ^= 1;
  }
  // C/D layout (verified m89/m91): col = lane&15, row = quad*4 + reg
  unsigned char ca[8], cb[4];
#pragma unroll
  for (int mi = 0; mi < 2; ++mi)
#pragma unroll
    for (int r = 0; r < 4; ++r)
      ca[mi * 4 + r] = gcode[sA + wr + mi * 16 + quad * 4 + r];
#pragma unroll
  for (int ni = 0; ni < 4; ++ni) cb[ni] = gcode[rowB + wc + ni * 16 + l16];
  const bool ov = tile_overlap(gcode, sA, 127, rowB);
  _Float16* St = Sc + (size_t)bid * 16384;

  float rowsum[8] = {};
  float colsum[4] = {};
#pragma unroll
  for (int mi = 0; mi < 2; ++mi)
#pragma unroll
    for (int ni = 0; ni < 4; ++ni)
#pragma unroll
      for (int r = 0; r < 4; ++r) {
        const float s = acc[mi][ni][r] * 10.0f;
        const float ex = __expf(s);
        const int a = ca[mi * 4 + r], b = cb[ni];
        const bool diff = a != b;
        rowsum[mi * 4 + r] += (b <= 2 && diff) ? ex : 0.f;
        colsum[ni] += (a <= 2 && diff) ? ex : 0.f;
        if (ov)
          St[(wr + mi * 16 + quad * 4 + r) * 128 + wc + ni * 16 + l16] =
              (_Float16)s;
      }
#pragma unroll
  for (int off = 1; off < 16; off <<= 1)
#pragma unroll
    for (int k = 0; k < 8; ++k) rowsum[k] += __shfl_xor(rowsum[k], off);
  if (l16 == 0) {
    const int sreal = bj * 4 + (wave & 1);
    const int szero = bj * 4 + 2 + (wave & 1);
    const size_t r0 = sA + wr + quad * 4;
    float4 v0 = {rowsum[0], rowsum[1], rowsum[2], rowsum[3]};
    float4 v1 = {rowsum[4], rowsum[5], rowsum[6], rowsum[7]};
    const float4 z = {0.f, 0.f, 0.f, 0.f};
    *(float4*)(P + (size_t)sreal * Nv + r0) = v0;
    *(float4*)(P + (size_t)sreal * Nv + r0 + 16) = v1;
    *(float4*)(P + (size_t)szero * Nv + r0) = z;
    *(float4*)(P + (size_t)szero * Nv + r0 + 16) = z;
  }
  if (bi != bj) {
#pragma unroll
    for (int off = 16; off < 64; off <<= 1)
#pragma unroll
      for (int ni = 0; ni < 4; ++ni) colsum[ni] += __shfl_xor(colsum[ni], off);
    if (quad == 0) {
      const int s = bi * 4 + (wave >> 1);
#pragma unroll
      for (int ni = 0; ni < 4; ++ni)
        P[(size_t)s * Nv + rowB + wc + ni * 16 + l16] = colsum[ni];
    }
  }
}

// ---------------- K3: pass 2 + final loss (fused, atomic) -------------------
__global__ __launch_bounds__(256) void k_p2(
    const unsigned char* __restrict__ gcode, const int* __restrict__ hdr,
    const float* __restrict__ P, const _Float16* __restrict__ Sc,
    float* __restrict__ out, int Nv) {
  const int NTv = hdr[2];
  const int ntri = hdr[3];
  if ((int)blockIdx.x >= ntri) return;
  const int bid = xcd_swz(blockIdx.x, ntri);
  int bi, bj;
  tri_decode(bid, NTv, bi, bj);
  const size_t sA = (size_t)bi * 128;
  const size_t rowB = (size_t)bj * 128;
  const int t = threadIdx.x;
  const bool diag = (bi == bj);
  if (!tile_overlap(gcode, sA, 127, rowB)) return;

  const int c0 = hdr[4], c1 = hdr[5], c2 = hdr[6];
  const int vt = c0 + c1 + c2;
  __shared__ float E_s[256];
  __shared__ float colpart[128 * 17];
  __shared__ float sd[4];

  {  // E recompute from P, coalesced (consecutive t -> consecutive rows)
    const int ns = NTv * 4;
    const size_t g = (t < 128) ? (sA + t) : (rowB + (t - 128));
    float s0 = 0.f, s1 = 0.f, s2 = 0.f, s3 = 0.f;
    int k = 0;
    for (; k + 4 <= ns; k += 4) {
      s0 += P[(size_t)k * Nv + g];
      s1 += P[(size_t)(k + 1) * Nv + g];
      s2 += P[(size_t)(k + 2) * Nv + g];
      s3 += P[(size_t)(k + 3) * Nv + g];
    }
    for (; k < ns; ++k) s0 += P[(size_t)k * Nv + g];
    E_s[t] = (s0 + s1) + (s2 + s3);
  }
  __syncthreads();

  const _Float16* St = Sc + (size_t)bid * 16384;
  const int l8 = t & 15;  // col chunk: cols l8*8 .. +7
  const int rg = t >> 4;  // row group 0..15
  unsigned char cbv[8];
  float eB[8];
  {
    const uint2 cv = *(const uint2*)(gcode + rowB + l8 * 8);
    const unsigned char* cp = (const unsigned char*)&cv;
#pragma unroll
    for (int e = 0; e < 8; ++e) cbv[e] = cp[e];
#pragma unroll
    for (int e = 0; e < 8; ++e) eB[e] = E_s[128 + l8 * 8 + e];
  }
  float colsum[8] = {};
  float part = 0.f;
#pragma unroll
  for (int k = 0; k < 8; ++k) {
    const int row = k * 16 + rg;
    const int a = gcode[sA + row];
    const float eA = E_s[row];
    const float4 sv = *(const float4*)(St + (size_t)row * 128 + l8 * 8);
    const _Float16* hp = (const _Float16*)&sv;
    float rsum = 0.f;
#pragma unroll
    for (int e = 0; e < 8; ++e) {
      const int col = l8 * 8 + e;
      const float em = __expf(-(float)hp[e]);
      const bool pos =
          (a == cbv[e]) && (cbv[e] <= 2) && !(diag && row == col);
      rsum += pos ? __logf(1.f + eA * em) : 0.f;
      colsum[e] += pos ? __logf(1.f + eB[e] * em) : 0.f;
    }
#pragma unroll
    for (int off = 1; off < 16; off <<= 1) rsum += __shfl_xor(rsum, off);
    if (l8 == 0 && a <= 2) {
      const int cmy = (a == 0) ? c0 : ((a == 1) ? c1 : c2);
      if (vt - cmy > 0 && cmy >= 2) part += rsum / (float)(cmy - 1);
    }
  }
#pragma unroll
  for (int e = 0; e < 8; ++e) colpart[(l8 * 8 + e) * 17 + rg] = colsum[e];
  __syncthreads();
  if (t < 128 && !diag) {
    float cs = 0.f;
#pragma unroll
    for (int i = 0; i < 16; ++i) cs += colpart[t * 17 + i];
    const int b = gcode[rowB + t];
    if (b <= 2) {
      const int cmy = (b == 0) ? c0 : ((b == 1) ? c1 : c2);
      if (vt - cmy > 0 && cmy >= 2) part += cs / (float)(cmy - 1);
    }
  }
  if (diag && t < 128) {  // no-pos anchors (pos_cnt==0, has_neg)
    const int a = gcode[sA + t];
    if (a <= 2) {
      const int cmy = (a == 0) ? c0 : ((a == 1) ? c1 : c2);
      if (vt - cmy > 0 && cmy == 1)
        part += __logf(1.f + E_s[t] * __expf(-10.0f));
    }
  }
  // block reduce + single atomic
#pragma unroll
  for (int off = 32; off; off >>= 1) part += __shfl_down(part, off);
  if ((t & 63) == 0) sd[t >> 6] = part;
  __syncthreads();
  if (t == 0) {
    const float tot = sd[0] + sd[1] + sd[2] + sd[3];
    atomicAdd(out, tot / (float)hdr[7]);
  }
}

extern "C" void kernel_launch(void* const* d_in, const int* in_sizes, int n_in,
                              void* d_out, int out_size, void* d_ws,
                              size_t ws_size, hipStream_t stream) {
  const float* X = (const float*)d_in[0];
  const int* labels = (const int*)d_in[1];
  const int* bad = (const int*)d_in[2];
  const int Nv = in_sizes[1];
  const int Dv = in_sizes[0] / Nv;

  size_t off = 0;
  auto alloc = [&](size_t bytes) -> void* {
    size_t p = (off + 255) & ~(size_t)255;
    off = p + bytes;
    return (void*)((char*)d_ws + p);
  };
  const int NT = Nv / 128;
  const int ntri_max = NT * (NT + 1) / 2;
  __bf16* fn = (__bf16*)alloc((size_t)Nv * Dv * 2);
  float* P = (float*)alloc((size_t)Nv * 256 * 4);  // [slot][row]
  _Float16* Sc = (_Float16*)alloc((size_t)ntri_max * 16384 * 2);
  int* map = (int*)alloc((size_t)Nv * 4);
  unsigned char* gcode = (unsigned char*)alloc((size_t)Nv);
  int* hdr = (int*)alloc(64);
  if (off > ws_size) return;  // scratch too small: fail loudly at validation
  float* outp = (float*)d_out;

  const int NB = (Nv + 7) / 8;  // norm blocks; +1 scan block
  k_prep<<<NB + 1, 512, 0, stream>>>(X, labels, bad, map, hdr, fn, gcode,
                                     outp, Nv, Dv, NB);
  k_p1<<<ntri_max, 512, 0, stream>>>(fn, map, gcode, hdr, P, Sc, Nv, Dv);
  k_p2<<<ntri_max, 256, 0, stream>>>(gcode, hdr, P, Sc, outp, Nv);
}

// Round 6
// 122.165 us; speedup vs baseline: 1.1469x; 1.1469x over previous
//
#include <hip/hip_runtime.h>

typedef __bf16 bf16x8 __attribute__((ext_vector_type(8)));
typedef float f32x4 __attribute__((ext_vector_type(4)));

#define GLOAD_LDS16(g, l)                                                      \
  __builtin_amdgcn_global_load_lds(                                            \
      (const __attribute__((address_space(1))) void*)(g),                      \
      (__attribute__((address_space(3))) void*)(l), 16, 0, 0)

// R16 = R13 revert (proven 125.6us) + micro-fixes:
//  - k_p1 __launch_bounds__(512,4): grid is ~2 blocks/CU; the old 6-wave cap
//    (~85 VGPR) constrained the K-loop scheduler for residency we never get.
//  - k_scan int4-vectorized label/bad loads (shorter serial critical path).
// R14's map-gather regressed (-14.5us): consumer-side gather scatters k_p1's
// panel reads and kills L2 locality -- gather must stay in the producer.

// ---------------- K1: codes + stable label-partition scan (1 block) ---------
__global__ __launch_bounds__(1024) void k_scan(
    const int* __restrict__ labels, const int* __restrict__ bad,
    unsigned char* __restrict__ code, int* __restrict__ dst,
    int* __restrict__ hdr, __bf16* __restrict__ fng,
    unsigned char* __restrict__ gcode, float* __restrict__ out, int Nv,
    int Dv) {
  const int t = threadIdx.x;
  const int lane = t & 63, wv = t >> 6;
  const int per = Nv >> 10;  // 8 at Nv=8192 (multiple of 4)
  const int base = t * per;
  unsigned char lc[8];
  int cnt[3] = {0, 0, 0};
  {
    const int4* l4 = (const int4*)(labels + base);
    const int4* b4 = (const int4*)(bad + base);
    for (int k = 0; k < (per >> 2); ++k) {
      const int4 lv = l4[k];
      const int4 bv = b4[k];
      const int la[4] = {lv.x, lv.y, lv.z, lv.w};
      const int ba[4] = {bv.x, bv.y, bv.z, bv.w};
#pragma unroll
      for (int e = 0; e < 4; ++e) {
        const unsigned char c =
            (ba[e] == 0) ? (unsigned char)la[e] : (unsigned char)255;
        lc[k * 4 + e] = c;
        code[base + k * 4 + e] = c;
        if (c <= 2) cnt[c]++;
      }
    }
  }
  int inc0 = cnt[0], inc1 = cnt[1], inc2 = cnt[2];
#pragma unroll
  for (int off = 1; off < 64; off <<= 1) {
    const int a = __shfl_up(inc0, off);
    const int b = __shfl_up(inc1, off);
    const int c = __shfl_up(inc2, off);
    if (lane >= off) {
      inc0 += a;
      inc1 += b;
      inc2 += c;
    }
  }
  __shared__ int wt[16][3], wo[17][3];
  if (lane == 63) {
    wt[wv][0] = inc0;
    wt[wv][1] = inc1;
    wt[wv][2] = inc2;
  }
  __syncthreads();
  if (t == 0) {
    int s0 = 0, s1 = 0, s2 = 0;
    for (int w = 0; w < 16; ++w) {
      wo[w][0] = s0;
      wo[w][1] = s1;
      wo[w][2] = s2;
      s0 += wt[w][0];
      s1 += wt[w][1];
      s2 += wt[w][2];
    }
    wo[16][0] = s0;
    wo[16][1] = s1;
    wo[16][2] = s2;
  }
  __syncthreads();
  const int C0 = wo[16][0], C1 = wo[16][1], C2 = wo[16][2];
  int run[3];
  run[0] = wo[wv][0] + inc0 - cnt[0];
  run[1] = C0 + wo[wv][1] + inc1 - cnt[1];
  run[2] = C0 + C1 + wo[wv][2] + inc2 - cnt[2];
  for (int k = 0; k < per; ++k) {
    const int c = lc[k];
    dst[base + k] = (c <= 2) ? run[c]++ : -1;
  }
  const int M = C0 + C1 + C2;
  const int Mpad = (M + 127) & ~127;
  if (t == 0) {
    const int NTv = Mpad >> 7;
    hdr[0] = M;
    hdr[1] = Mpad;
    hdr[2] = NTv;
    hdr[3] = NTv * (NTv + 1) / 2;
    hdr[4] = C0;
    hdr[5] = C1;
    hdr[6] = C2;
    int count = 1;
    if (C0 >= 2 && M > C0) count += C0;
    if (C1 >= 2 && M > C1) count += C1;
    if (C2 >= 2 && M > C2) count += C2;
    hdr[7] = count;
    out[0] = 0.f;  // k_p2 atomicAdds into this
  }
  for (int i = M + t; i < Mpad; i += 1024) gcode[i] = 255;
  const int nv4 = (Mpad - M) * (Dv >> 3);
  float4* fp = (float4*)(fng + (size_t)M * Dv);
  const float4 z = {0.f, 0.f, 0.f, 0.f};
  for (int i = t; i < nv4; i += 1024) fp[i] = z;
}

// ---------------- K2: normalize, one row per wave ---------------------------
__global__ __launch_bounds__(512) void k_norm(const float* __restrict__ X,
                                              const unsigned char* __restrict__
                                                  code,
                                              const int* __restrict__ dst,
                                              __bf16* __restrict__ fng,
                                              unsigned char* __restrict__ gcode,
                                              int Nv, int Dv) {
  const int t = threadIdx.x;
  const int tl = t & 63;
  const int row = blockIdx.x * 8 + (t >> 6);
  if (row >= Nv) return;
  const unsigned char c = code[row];
  if (c > 2) return;  // wave-uniform skip
  const float4* xr = (const float4*)(X + (size_t)row * Dv);
  if (Dv == 512) {
    const float4 v0 = xr[tl * 2];
    const float4 v1 = xr[tl * 2 + 1];
    float ss = v0.x * v0.x + v0.y * v0.y + v0.z * v0.z + v0.w * v0.w +
               v1.x * v1.x + v1.y * v1.y + v1.z * v1.z + v1.w * v1.w;
#pragma unroll
    for (int off = 1; off < 64; off <<= 1) ss += __shfl_xor(ss, off);
    const float inv = 1.0f / sqrtf(ss);
    const int g = dst[row];
    bf16x8 o;
    o[0] = (__bf16)(v0.x * inv);
    o[1] = (__bf16)(v0.y * inv);
    o[2] = (__bf16)(v0.z * inv);
    o[3] = (__bf16)(v0.w * inv);
    o[4] = (__bf16)(v1.x * inv);
    o[5] = (__bf16)(v1.y * inv);
    o[6] = (__bf16)(v1.z * inv);
    o[7] = (__bf16)(v1.w * inv);
    *(bf16x8*)(fng + (size_t)g * Dv + tl * 8) = o;
    if (tl == 0) gcode[g] = c;
    return;
  }
  // generic path
  float ss = 0.f;
  for (int idx = tl; idx < (Dv >> 2); idx += 64) {
    const float4 v = xr[idx];
    ss += v.x * v.x + v.y * v.y + v.z * v.z + v.w * v.w;
  }
#pragma unroll
  for (int off = 1; off < 64; off <<= 1) ss += __shfl_xor(ss, off);
  const float inv = 1.0f / sqrtf(ss);
  const int g = dst[row];
  for (int idx = tl; idx < (Dv >> 3); idx += 64) {
    const float4 u0 = xr[idx * 2];
    const float4 u1 = xr[idx * 2 + 1];
    bf16x8 o;
    o[0] = (__bf16)(u0.x * inv);
    o[1] = (__bf16)(u0.y * inv);
    o[2] = (__bf16)(u0.z * inv);
    o[3] = (__bf16)(u0.w * inv);
    o[4] = (__bf16)(u1.x * inv);
    o[5] = (__bf16)(u1.y * inv);
    o[6] = (__bf16)(u1.z * inv);
    o[7] = (__bf16)(u1.w * inv);
    *(bf16x8*)(fng + (size_t)g * Dv + idx * 8) = o;
  }
  if (tl == 0) gcode[g] = c;
}

__device__ __forceinline__ void tri_decode(int blk, int NT, int& bi, int& bj) {
  int b = 0, rem = blk, span = NT;
  while (rem >= span) {
    rem -= span;
    b++;
    span--;
  }
  bi = b;
  bj = b + rem;
}

// bijective XCD swizzle over [0,n) (m204 formula)
__device__ __forceinline__ int xcd_swz(int w, int n) {
  const int q = n >> 3, r = n & 7, x = w & 7, o = w >> 3;
  return (x < r ? x * (q + 1) : r * (q + 1) + (x - r) * q) + o;
}

__device__ __forceinline__ bool tile_overlap(const unsigned char* gcode,
                                             size_t sA, int lastA,
                                             size_t rowB) {
  const int la0 = gcode[sA], la1 = gcode[sA + lastA];
  const int lb0 = gcode[rowB], lb1 = gcode[rowB + 127];
  const int hiA = la1 > 2 ? 2 : la1;
  const int hiB = lb1 > 2 ? 2 : lb1;
  const int lo = la0 > lb0 ? la0 : lb0;
  const int hi = hiA < hiB ? hiA : hiB;
  return (la0 <= 2) && (lb0 <= 2) && (lo <= hi);
}

// ---------------- K3: pass 1 — exp-sums, 128x128 tiles ----------------------
__global__ __launch_bounds__(512, 4) void k_p1(
    const __bf16* __restrict__ fng, const unsigned char* __restrict__ gcode,
    const int* __restrict__ hdr, float* __restrict__ P,
    _Float16* __restrict__ Sc, int Nv, int Dv) {
  const int NTv = hdr[2];
  const int ntri = hdr[3];
  int bid = blockIdx.x;
  if (bid >= ntri) return;
  bid = xcd_swz(bid, ntri);
  int bi, bj;
  tri_decode(bid, NTv, bi, bj);
  const size_t sA = (size_t)bi * 128;
  const size_t rowB = (size_t)bj * 128;
  __shared__ __align__(16) __bf16 As[2][128 * 32];
  __shared__ __align__(16) __bf16 Bs[2][128 * 32];

  const int t = threadIdx.x;
  const int lane = t & 63;
  const int wave = t >> 6;
  const int quad = lane >> 4;
  const int l16 = lane & 15;
  const int wr = (wave >> 1) * 32;
  const int wc = (wave & 1) * 64;
  const int r4 = t >> 2, q4 = t & 3;

  f32x4 acc[2][4] = {};
  auto stage = [&](int k0, int b) {
    GLOAD_LDS16(fng + (sA + r4) * Dv + k0 + q4 * 8,
                &As[b][(size_t)wave * 64 * 8]);
    GLOAD_LDS16(fng + (rowB + r4) * Dv + k0 + q4 * 8,
                &Bs[b][(size_t)wave * 64 * 8]);
  };
  stage(0, 0);
  int buf = 0;
  for (int k0 = 0; k0 < Dv; k0 += 32) {
    __syncthreads();  // drains vmcnt: buf loads done; prev reads done
    if (k0 + 32 < Dv) stage(k0 + 32, buf ^ 1);
    bf16x8 af[2], bfv[4];
#pragma unroll
    for (int mi = 0; mi < 2; ++mi)
      af[mi] = *(const bf16x8*)&As[buf][(wr + mi * 16 + l16) * 32 + quad * 8];
#pragma unroll
    for (int ni = 0; ni < 4; ++ni)
      bfv[ni] = *(const bf16x8*)&Bs[buf][(wc + ni * 16 + l16) * 32 + quad * 8];
#pragma unroll
    for (int mi = 0; mi < 2; ++mi)
#pragma unroll
      for (int ni = 0; ni < 4; ++ni)
        acc[mi][ni] = __builtin_amdgcn_mfma_f32_16x16x32_bf16(
            af[mi], bfv[ni], acc[mi][ni], 0, 0, 0);
    buf ^= 1;
  }
  // C/D layout (verified m89/m91): col = lane&15, row = quad*4 + reg
  unsigned char ca[8], cb[4];
#pragma unroll
  for (int mi = 0; mi < 2; ++mi)
#pragma unroll
    for (int r = 0; r < 4; ++r)
      ca[mi * 4 + r] = gcode[sA + wr + mi * 16 + quad * 4 + r];
#pragma unroll
  for (int ni = 0; ni < 4; ++ni) cb[ni] = gcode[rowB + wc + ni * 16 + l16];
  const bool ov = tile_overlap(gcode, sA, 127, rowB);
  _Float16* St = Sc + (size_t)bid * 16384;

  float rowsum[8] = {};
  float colsum[4] = {};
#pragma unroll
  for (int mi = 0; mi < 2; ++mi)
#pragma unroll
    for (int ni = 0; ni < 4; ++ni)
#pragma unroll
      for (int r = 0; r < 4; ++r) {
        const float s = acc[mi][ni][r] * 10.0f;
        const float ex = __expf(s);
        const int a = ca[mi * 4 + r], b = cb[ni];
        const bool diff = a != b;
        rowsum[mi * 4 + r] += (b <= 2 && diff) ? ex : 0.f;
        colsum[ni] += (a <= 2 && diff) ? ex : 0.f;
        if (ov)
          St[(wr + mi * 16 + quad * 4 + r) * 128 + wc + ni * 16 + l16] =
              (_Float16)s;
      }
#pragma unroll
  for (int off = 1; off < 16; off <<= 1)
#pragma unroll
    for (int k = 0; k < 8; ++k) rowsum[k] += __shfl_xor(rowsum[k], off);
  if (l16 == 0) {
    const int sreal = bj * 4 + (wave & 1);
    const int szero = bj * 4 + 2 + (wave & 1);
    const size_t r0 = sA + wr + quad * 4;
    float4 v0 = {rowsum[0], rowsum[1], rowsum[2], rowsum[3]};
    float4 v1 = {rowsum[4], rowsum[5], rowsum[6], rowsum[7]};
    const float4 z = {0.f, 0.f, 0.f, 0.f};
    *(float4*)(P + (size_t)sreal * Nv + r0) = v0;
    *(float4*)(P + (size_t)sreal * Nv + r0 + 16) = v1;
    *(float4*)(P + (size_t)szero * Nv + r0) = z;
    *(float4*)(P + (size_t)szero * Nv + r0 + 16) = z;
  }
  if (bi != bj) {
#pragma unroll
    for (int off = 16; off < 64; off <<= 1)
#pragma unroll
      for (int ni = 0; ni < 4; ++ni) colsum[ni] += __shfl_xor(colsum[ni], off);
    if (quad == 0) {
      const int s = bi * 4 + (wave >> 1);
#pragma unroll
      for (int ni = 0; ni < 4; ++ni)
        P[(size_t)s * Nv + rowB + wc + ni * 16 + l16] = colsum[ni];
    }
  }
}

// ---------------- K4: pass 2 + final loss (fused, atomic) -------------------
__global__ __launch_bounds__(256) void k_p2(
    const unsigned char* __restrict__ gcode, const int* __restrict__ hdr,
    const float* __restrict__ P, const _Float16* __restrict__ Sc,
    float* __restrict__ out, int Nv) {
  const int NTv = hdr[2];
  const int ntri = hdr[3];
  if ((int)blockIdx.x >= ntri) return;
  const int bid = xcd_swz(blockIdx.x, ntri);
  int bi, bj;
  tri_decode(bid, NTv, bi, bj);
  const size_t sA = (size_t)bi * 128;
  const size_t rowB = (size_t)bj * 128;
  const int t = threadIdx.x;
  const bool diag = (bi == bj);
  if (!tile_overlap(gcode, sA, 127, rowB)) return;

  const int c0 = hdr[4], c1 = hdr[5], c2 = hdr[6];
  const int vt = c0 + c1 + c2;
  __shared__ float E_s[256];
  __shared__ float colpart[128 * 17];
  __shared__ float sd[4];

  {  // E recompute from P, coalesced (consecutive t -> consecutive rows)
    const int ns = NTv * 4;
    const size_t g = (t < 128) ? (sA + t) : (rowB + (t - 128));
    float s0 = 0.f, s1 = 0.f, s2 = 0.f, s3 = 0.f;
    int k = 0;
    for (; k + 4 <= ns; k += 4) {
      s0 += P[(size_t)k * Nv + g];
      s1 += P[(size_t)(k + 1) * Nv + g];
      s2 += P[(size_t)(k + 2) * Nv + g];
      s3 += P[(size_t)(k + 3) * Nv + g];
    }
    for (; k < ns; ++k) s0 += P[(size_t)k * Nv + g];
    E_s[t] = (s0 + s1) + (s2 + s3);
  }
  __syncthreads();

  const _Float16* St = Sc + (size_t)bid * 16384;
  const int l8 = t & 15;  // col chunk: cols l8*8 .. +7
  const int rg = t >> 4;  // row group 0..15
  unsigned char cbv[8];
  float eB[8];
  {
    const uint2 cv = *(const uint2*)(gcode + rowB + l8 * 8);
    const unsigned char* cp = (const unsigned char*)&cv;
#pragma unroll
    for (int e = 0; e < 8; ++e) cbv[e] = cp[e];
#pragma unroll
    for (int e = 0; e < 8; ++e) eB[e] = E_s[128 + l8 * 8 + e];
  }
  float colsum[8] = {};
  float part = 0.f;
#pragma unroll
  for (int k = 0; k < 8; ++k) {
    const int row = k * 16 + rg;
    const int a = gcode[sA + row];
    const float eA = E_s[row];
    const float4 sv = *(const float4*)(St + (size_t)row * 128 + l8 * 8);
    const _Float16* hp = (const _Float16*)&sv;
    float rsum = 0.f;
#pragma unroll
    for (int e = 0; e < 8; ++e) {
      const int col = l8 * 8 + e;
      const float em = __expf(-(float)hp[e]);
      const bool pos =
          (a == cbv[e]) && (cbv[e] <= 2) && !(diag && row == col);
      rsum += pos ? __logf(1.f + eA * em) : 0.f;
      colsum[e] += pos ? __logf(1.f + eB[e] * em) : 0.f;
    }
#pragma unroll
    for (int off = 1; off < 16; off <<= 1) rsum += __shfl_xor(rsum, off);
    if (l8 == 0 && a <= 2) {
      const int cmy = (a == 0) ? c0 : ((a == 1) ? c1 : c2);
      if (vt - cmy > 0 && cmy >= 2) part += rsum / (float)(cmy - 1);
    }
  }
#pragma unroll
  for (int e = 0; e < 8; ++e) colpart[(l8 * 8 + e) * 17 + rg] = colsum[e];
  __syncthreads();
  if (t < 128 && !diag) {
    float cs = 0.f;
#pragma unroll
    for (int i = 0; i < 16; ++i) cs += colpart[t * 17 + i];
    const int b = gcode[rowB + t];
    if (b <= 2) {
      const int cmy = (b == 0) ? c0 : ((b == 1) ? c1 : c2);
      if (vt - cmy > 0 && cmy >= 2) part += cs / (float)(cmy - 1);
    }
  }
  if (diag && t < 128) {  // no-pos anchors (pos_cnt==0, has_neg)
    const int a = gcode[sA + t];
    if (a <= 2) {
      const int cmy = (a == 0) ? c0 : ((a == 1) ? c1 : c2);
      if (vt - cmy > 0 && cmy == 1)
        part += __logf(1.f + E_s[t] * __expf(-10.0f));
    }
  }
  // block reduce + single atomic
#pragma unroll
  for (int off = 32; off; off >>= 1) part += __shfl_down(part, off);
  if ((t & 63) == 0) sd[t >> 6] = part;
  __syncthreads();
  if (t == 0) {
    const float tot = sd[0] + sd[1] + sd[2] + sd[3];
    atomicAdd(out, tot / (float)hdr[7]);
  }
}

extern "C" void kernel_launch(void* const* d_in, const int* in_sizes, int n_in,
                              void* d_out, int out_size, void* d_ws,
                              size_t ws_size, hipStream_t stream) {
  const float* X = (const float*)d_in[0];
  const int* labels = (const int*)d_in[1];
  const int* bad = (const int*)d_in[2];
  const int Nv = in_sizes[1];
  const int Dv = in_sizes[0] / Nv;

  size_t off = 0;
  auto alloc = [&](size_t bytes) -> void* {
    size_t p = (off + 255) & ~(size_t)255;
    off = p + bytes;
    return (void*)((char*)d_ws + p);
  };
  const int NT = Nv / 128;
  const int ntri_max = NT * (NT + 1) / 2;
  __bf16* fng = (__bf16*)alloc((size_t)Nv * Dv * 2);
  float* P = (float*)alloc((size_t)Nv * 256 * 4);  // [slot][row]
  _Float16* Sc = (_Float16*)alloc((size_t)ntri_max * 16384 * 2);
  int* dst = (int*)alloc((size_t)Nv * 4);
  unsigned char* code = (unsigned char*)alloc((size_t)Nv);
  unsigned char* gcode = (unsigned char*)alloc((size_t)Nv);
  int* hdr = (int*)alloc(64);
  if (off > ws_size) return;  // scratch too small: fail loudly at validation
  float* outp = (float*)d_out;

  k_scan<<<1, 1024, 0, stream>>>(labels, bad, code, dst, hdr, fng, gcode,
                                 outp, Nv, Dv);
  k_norm<<<(Nv + 7) / 8, 512, 0, stream>>>(X, code, dst, fng, gcode, Nv, Dv);
  k_p1<<<ntri_max, 512, 0, stream>>>(fng, gcode, hdr, P, Sc, Nv, Dv);
  k_p2<<<ntri_max, 256, 0, stream>>>(gcode, hdr, P, Sc, outp, Nv);
}